// Round 1
// baseline (226.404 us; speedup 1.0000x reference)
//
#include <hip/hip_runtime.h>

#define ETA_MIN 2.302585092994046f  // log(10)
#define ETA_MAX 20.0f

// Native clang vector type — HIP's float4 struct is rejected by
// __builtin_nontemporal_load/store; ext_vector_type(4) float is accepted.
typedef float v4f __attribute__((ext_vector_type(4)));

constexpr int BLOCK  = 256;
constexpr int UNROLL = 4;   // 4 independent 16B loads in flight per thread

// Elementwise: w_i = (loss_i > eta) ? 0 : 1 - loss_i/eta,
// eta = clamp(eta_value[0], ETA_MIN, ETA_MAX).
// Memory-bound: 256 MB total traffic, roofline ~41 us at 6.3 TB/s.
// Changes vs previous version:
//  - grid capped at 2048 blocks (8/CU) + grid-stride loop: amortizes block
//    launch/retire over 256 B/thread instead of 16 B/thread (G11).
//  - UNROLL=4 batched loads-then-stores: 4 outstanding nontemporal loads per
//    lane for MLP instead of 1 (G7). Static indexing -> stays in VGPRs.
__global__ __launch_bounds__(BLOCK) void Weightfun_78374563217418_kernel(
    const v4f* __restrict__ loss, const float* __restrict__ eta_ptr,
    v4f* __restrict__ out, int n4) {
    // uniform scalar broadcast load; clamped per reference
    float eta = fminf(fmaxf(eta_ptr[0], ETA_MIN), ETA_MAX);
    float inv_eta = 1.0f / eta;  // one precise divide per thread

    const int stride = (int)gridDim.x * BLOCK;  // total threads, v4f units
    const int i0     = (int)blockIdx.x * BLOCK + (int)threadIdx.x;

    for (int base = i0; base < n4; base += stride * UNROLL) {
        v4f  l[UNROLL];
        bool ok[UNROLL];
        // Phase 1: issue all loads (independent, 4 in flight per lane)
#pragma unroll
        for (int u = 0; u < UNROLL; ++u) {
            int idx = base + u * stride;
            ok[u] = idx < n4;
            if (ok[u]) l[u] = __builtin_nontemporal_load(&loss[idx]);
        }
        // Phase 2: compute + store
#pragma unroll
        for (int u = 0; u < UNROLL; ++u) {
            if (ok[u]) {
                v4f v = l[u];
                v4f w;
                w.x = (v.x > eta) ? 0.0f : fmaf(-v.x, inv_eta, 1.0f);
                w.y = (v.y > eta) ? 0.0f : fmaf(-v.y, inv_eta, 1.0f);
                w.z = (v.z > eta) ? 0.0f : fmaf(-v.z, inv_eta, 1.0f);
                w.w = (v.w > eta) ? 0.0f : fmaf(-v.w, inv_eta, 1.0f);
                __builtin_nontemporal_store(w, &out[base + u * stride]);
            }
        }
    }
}

extern "C" void kernel_launch(void* const* d_in, const int* in_sizes, int n_in,
                              void* d_out, int out_size, void* d_ws, size_t ws_size,
                              hipStream_t stream) {
    const v4f*   loss = (const v4f*)d_in[0];
    const float* eta  = (const float*)d_in[1];
    v4f*         out  = (v4f*)d_out;

    int n  = in_sizes[0];   // 33554432 = 2^25, divisible by 4
    int n4 = n / 4;         // 8388608 v4f elements

    int per_block = BLOCK * UNROLL;
    int grid = (n4 + per_block - 1) / per_block;
    if (grid > 2048) grid = 2048;  // 8 blocks/CU; grid-stride covers the rest
    // n4 = 2^23, stride*UNROLL = 2^21 -> exactly 4 outer iterations, no tail

    Weightfun_78374563217418_kernel<<<grid, BLOCK, 0, stream>>>(loss, eta, out, n4);
}